// Round 9
// baseline (215.712 us; speedup 1.0000x reference)
//
#include <hip/hip_runtime.h>
#include <hip/hip_bf16.h>

#define N_NODES 50000
#define N_GRAPHS 64
#define HID 100
#define HP 104            // padded cols: 13 chunks of 8

#define BKE  4096         // edges per block in p1/p3
#define NBIN 196          // buckets of 256 nodes: ceil(50000/256)
#define MAXBLK 256        // max edge-blocks supported (E <= 1M)

#define NSUB2 391         // ceil(N/128) node sub-blocks for 2-chunk gather groups
#define NSUB1 196         // ceil(N/256) for 1-chunk groups

// ---- workspace layout (float offsets) ----
// HS/H1/ACC are CHUNK-MAJOR bf16: [13][N_NODES][8]
#define OFF_DINV 0
#define OFF_CNTF 50048
#define OFF_POOL 50112
#define OFF_WT1  50176                    // bf16 [112][128] = 7168 floats
#define OFF_WT2  57344
#define OFF_HS   64512                    // 2.6M floats
#define OFF_H1   2664512
#define OFF_ACC  5264512
#define OFF_ROWPTR 7864512                // N+1 ints
#define OFF_EIDX   7914560                // E ushorts (round-9: was int)
#define OFF_BE     8714560                // E uints (packed (src<<16)|dst, bucketed)
#define OFF_BBINS  9514560                // [MAXBLK][NBIN] ints
#define OFF_BOFF   9565760                // [MAXBLK][NBIN] ints
#define OFF_BTOT   9616960                // NBIN ints
#define OFF_BBASE  9617216                // NBIN+1 ints

typedef __attribute__((ext_vector_type(8))) short short8;
typedef __attribute__((ext_vector_type(4))) float floatx4;

__device__ inline float b2f(unsigned int u) {
    union { unsigned int v; float f; } x; x.v = u << 16; return x.f;
}
__device__ inline unsigned short f2b(float f) {
    union { float f; unsigned int v; } x; x.f = f;
    unsigned int r = (x.v + 0x7fffu + ((x.v >> 16) & 1u)) >> 16;   // RTNE
    return (unsigned short)r;
}

__global__ void k_zero(float* __restrict__ pool, float* __restrict__ cntf) {
    int i = threadIdx.x;
    if (i < N_GRAPHS) { pool[i] = 0.0f; cntf[i] = 0.0f; }
}

// W [KSRC][100] f32 -> Wt [112][128] bf16 (transposed, zero-padded)
__global__ void k_wt(const float* __restrict__ W, int KSRC, unsigned short* __restrict__ Wt) {
    int idx = blockIdx.x * 256 + threadIdx.x;
    if (idx >= 112 * 128) return;
    int c = idx >> 7, k = idx & 127;
    float v = (k < KSRC && c < HID) ? W[k * HID + c] : 0.0f;
    Wt[c * 128 + k] = f2b(v);
}

// ---- CSR build: two-level counting sort ----
__global__ __launch_bounds__(256) void k_p1(const int* __restrict__ dst, int E,
                                            int* __restrict__ bbins) {
    __shared__ int hist[256];
    const int t = threadIdx.x, b = blockIdx.x;
    hist[t] = 0;
    __syncthreads();
    int e0 = b * BKE, e1 = min(e0 + BKE, E);
    for (int e = e0 + t; e < e1; e += 256) atomicAdd(&hist[dst[e] >> 8], 1);
    __syncthreads();
    if (t < NBIN) bbins[b * NBIN + t] = hist[t];
}

__global__ __launch_bounds__(256) void k_p2a(const int* __restrict__ bbins, int nb,
                                             int* __restrict__ boff, int* __restrict__ btot) {
    __shared__ int sb[256];
    const int t = threadIdx.x, j = blockIdx.x;
    int v = (t < nb) ? bbins[t * NBIN + j] : 0;
    sb[t] = v;
    __syncthreads();
    for (int off = 1; off < 256; off <<= 1) {
        int u = (t >= off) ? sb[t - off] : 0;
        __syncthreads();
        sb[t] += u;
        __syncthreads();
    }
    if (t < nb) boff[t * NBIN + j] = sb[t] - v;
    if (t == 255) btot[j] = sb[255];
}

__global__ __launch_bounds__(256) void k_p2b(const int* __restrict__ btot, int E,
                                             int* __restrict__ bbase, int* __restrict__ rowptr) {
    __shared__ int sb[256];
    const int t = threadIdx.x;
    int v = (t < NBIN) ? btot[t] : 0;
    sb[t] = v;
    __syncthreads();
    for (int off = 1; off < 256; off <<= 1) {
        int u = (t >= off) ? sb[t - off] : 0;
        __syncthreads();
        sb[t] += u;
        __syncthreads();
    }
    if (t < NBIN) bbase[t] = sb[t] - v;
    if (t == 0) { bbase[NBIN] = E; rowptr[N_NODES] = E; }
}

__global__ __launch_bounds__(256) void k_p3(const int* __restrict__ src, const int* __restrict__ dst,
                                            int E, const int* __restrict__ boff,
                                            const int* __restrict__ bbase,
                                            unsigned int* __restrict__ bE) {
    __shared__ unsigned int stage[BKE];
    __shared__ int hist[256], pref[256], cur[256], sb[256], offr[NBIN];
    const int t = threadIdx.x, b = blockIdx.x;
    hist[t] = 0;
    if (t < NBIN) offr[t] = boff[b * NBIN + t] + bbase[t];
    __syncthreads();
    int e0 = b * BKE, e1 = min(e0 + BKE, E), n = e1 - e0;
    unsigned int mine[BKE / 256];
    int cnt = 0;
    for (int e = e0 + t; e < e1; e += 256) {
        unsigned int v = ((unsigned int)src[e] << 16) | (unsigned int)dst[e];
        mine[cnt++] = v;
        atomicAdd(&hist[(v >> 8) & 255], 1);
    }
    __syncthreads();
    sb[t] = hist[t];
    __syncthreads();
    for (int off = 1; off < 256; off <<= 1) {
        int v = (t >= off) ? sb[t - off] : 0;
        __syncthreads();
        sb[t] += v;
        __syncthreads();
    }
    pref[t] = sb[t] - hist[t];
    cur[t] = pref[t];
    __syncthreads();
    for (int c = 0; c < cnt; ++c) {
        unsigned int v = mine[c];
        int p = atomicAdd(&cur[(v >> 8) & 255], 1);
        stage[p] = v;
    }
    __syncthreads();
    for (int i = t; i < n; i += 256) {
        unsigned int v = stage[i];
        int bin = (v >> 8) & 255;
        bE[offr[bin] + (i - pref[bin])] = v;
    }
}

// p4: per-bucket sort by node -> rowptr, dinv, eidx (uint16 src ids)
__global__ __launch_bounds__(256) void k_p4(const unsigned int* __restrict__ bE,
                                            const int* __restrict__ bbase,
                                            int* __restrict__ rowptr, unsigned short* __restrict__ eidx,
                                            float* __restrict__ dinv) {
    __shared__ int hist[256], pref[256], cur[256], sb[256];
    const int t = threadIdx.x, b = blockIdx.x;
    const int eBase = bbase[b], eEnd = bbase[b + 1], n = eEnd - eBase;
    hist[t] = 0;
    __syncthreads();
    for (int i = t; i < n; i += 256) atomicAdd(&hist[bE[eBase + i] & 255], 1);
    __syncthreads();
    sb[t] = hist[t];
    __syncthreads();
    for (int off = 1; off < 256; off <<= 1) {
        int v = (t >= off) ? sb[t - off] : 0;
        __syncthreads();
        sb[t] += v;
        __syncthreads();
    }
    pref[t] = sb[t] - hist[t];
    cur[t] = pref[t];
    int node = (b << 8) + t;
    if (node < N_NODES) {
        rowptr[node] = eBase + pref[t];
        dinv[node] = rsqrtf((float)(hist[t] + 1));   // +1 self loop
    }
    __syncthreads();
    for (int i = t; i < n; i += 256) {
        unsigned int v = bE[eBase + i];
        int p = atomicAdd(&cur[v & 255], 1);
        eidx[eBase + p] = (unsigned short)(v >> 16);
    }
}

// MFMA bf16 GEMM: out[ch][i][j] = f2b(dinv[i] * sum_k A[i][k] * W[k][8ch+j]) (chunk-major out)
template<bool ABF16>
__global__ __launch_bounds__(256) void k_gemm(const void* __restrict__ Asrc,
                                              const unsigned short* __restrict__ Wt, // [112][128]
                                              const float* __restrict__ dinv,
                                              unsigned short* __restrict__ out) {
    __shared__ __align__(16) unsigned short xs[64][136];
    __shared__ __align__(16) unsigned short ws[112][136];
    const int t = threadIdx.x;
    const int base = blockIdx.x * 64;

    for (int idx = t; idx < 112 * 64; idx += 256) {
        int c = idx >> 6, u = idx & 63;
        *(unsigned int*)&ws[c][2 * u] = ((const unsigned int*)Wt)[idx];
    }
    if (ABF16) {
        const unsigned short* A = (const unsigned short*)Asrc;   // chunk-major [13][N][8]
        for (int idx = t; idx < 64 * 16; idx += 256) {
            int q = idx >> 6, r = idx & 63;     // q = chunk, r = row-in-tile (coalesced per q)
            int row = base + r;
            uint4 v = make_uint4(0, 0, 0, 0);
            if (q < 13 && row < N_NODES)
                v = *(const uint4*)(A + ((size_t)q * N_NODES + row) * 8);
            *(uint4*)&xs[r][8 * q] = v;
        }
    } else {
        const float* A = (const float*)Asrc;                     // [N][128] f32
        for (int idx = t; idx < 64 * 32; idx += 256) {
            int r = idx >> 5, q = idx & 31;
            int row = base + r;
            ushort4 p;
            if (row < N_NODES) {
                float4 v = ((const float4*)(A + (size_t)row * 128))[q];
                p.x = f2b(v.x); p.y = f2b(v.y); p.z = f2b(v.z); p.w = f2b(v.w);
            } else p = make_ushort4(0, 0, 0, 0);
            *(ushort4*)&xs[r][4 * q] = p;
        }
    }
    __syncthreads();

    const int lane = t & 63, w = t >> 6;
    const int g = lane >> 4, cl = lane & 15;

    floatx4 acc[7];
#pragma unroll
    for (int n = 0; n < 7; ++n) acc[n] = (floatx4){0.f, 0.f, 0.f, 0.f};

#pragma unroll
    for (int kc = 0; kc < 4; ++kc) {
        short8 a = *(const short8*)&xs[w * 16 + cl][kc * 32 + 8 * g];
#pragma unroll
        for (int n = 0; n < 7; ++n) {
            short8 b = *(const short8*)&ws[n * 16 + cl][kc * 32 + 8 * g];
            acc[n] = __builtin_amdgcn_mfma_f32_16x16x32_bf16(a, b, acc[n], 0, 0, 0);
        }
    }

    float di[4]; int grows[4];
#pragma unroll
    for (int r = 0; r < 4; ++r) {
        grows[r] = base + w * 16 + 4 * g + r;
        di[r] = (grows[r] < N_NODES) ? dinv[grows[r]] : 0.0f;
    }
#pragma unroll
    for (int n = 0; n < 7; ++n) {
        int gcol = n * 16 + cl;
        int ch = gcol >> 3, j = gcol & 7;
        if (ch >= 13) continue;
#pragma unroll
        for (int r = 0; r < 4; ++r) {
            if (grows[r] < N_NODES)
                out[((size_t)ch * N_NODES + grows[r]) * 8 + j] = f2b(acc[n][r] * di[r]);
        }
    }
}

// gather (round-9): chunk-major, XCD-pinned chunk groups, 4-deep MLP unroll.
// blockIdx&7 = chunk group (XCD round-robin): g<5 -> chunks {g,g+8}, 128 nodes/block;
// g>=5 -> chunk g, 256 nodes/block. Per-XCD L2 WS ~3.4MB (slice+eidx16+rowptr).
#define ACC8(v) do { \
    s[0] += b2f((v).x & 0xffff); s[1] += b2f((v).x >> 16); \
    s[2] += b2f((v).y & 0xffff); s[3] += b2f((v).y >> 16); \
    s[4] += b2f((v).z & 0xffff); s[5] += b2f((v).z >> 16); \
    s[6] += b2f((v).w & 0xffff); s[7] += b2f((v).w >> 16); } while (0)

template<bool FIN1>
__global__ __launch_bounds__(256) void k_gather(const int* __restrict__ rowptr,
                                                const unsigned short* __restrict__ eidx,
                                                const unsigned short* __restrict__ hs,  // [13][N][8]
                                                const float* __restrict__ dinv,
                                                const float* __restrict__ b1,
                                                unsigned short* __restrict__ outp) {   // [13][N][8]
    const int g = blockIdx.x & 7, sub = blockIdx.x >> 3;
    const int t = threadIdx.x;
    int i, c;
    if (g < 5) { i = sub * 128 + (t >> 1); c = g + 8 * (t & 1); }
    else       { if (sub >= NSUB1) return; i = sub * 256 + t; c = g; }
    if (i >= N_NODES) return;

    const unsigned short* hc = hs + (size_t)c * N_NODES * 8;
    float s[8];
    uint4 sv = *(const uint4*)(hc + (size_t)i * 8);   // self loop
    s[0] = b2f(sv.x & 0xffff); s[1] = b2f(sv.x >> 16);
    s[2] = b2f(sv.y & 0xffff); s[3] = b2f(sv.y >> 16);
    s[4] = b2f(sv.z & 0xffff); s[5] = b2f(sv.z >> 16);
    s[6] = b2f(sv.w & 0xffff); s[7] = b2f(sv.w >> 16);

    int e = rowptr[i];
    const int end = rowptr[i + 1];
    for (; e + 4 <= end; e += 4) {
        int n0 = eidx[e], n1 = eidx[e + 1], n2 = eidx[e + 2], n3 = eidx[e + 3];
        uint4 v0 = *(const uint4*)(hc + (size_t)n0 * 8);
        uint4 v1 = *(const uint4*)(hc + (size_t)n1 * 8);
        uint4 v2 = *(const uint4*)(hc + (size_t)n2 * 8);
        uint4 v3 = *(const uint4*)(hc + (size_t)n3 * 8);
        ACC8(v0); ACC8(v1); ACC8(v2); ACC8(v3);
    }
    for (; e < end; ++e) {
        uint4 v = *(const uint4*)(hc + (size_t)eidx[e] * 8);
        ACC8(v);
    }

    unsigned short o[8];
    if (FIN1) {
        float di = dinv[i];
        if (c < 12) {
#pragma unroll
            for (int j = 0; j < 8; ++j) o[j] = f2b(tanhf(di * s[j] + b1[8 * c + j]));
        } else {
#pragma unroll
            for (int j = 0; j < 4; ++j) o[j] = f2b(tanhf(di * s[j] + b1[96 + j]));
#pragma unroll
            for (int j = 4; j < 8; ++j) o[j] = 0;
        }
    } else {
#pragma unroll
        for (int j = 0; j < 8; ++j) o[j] = f2b(s[j]);
    }
    uint4 ov;
    ov.x = (unsigned int)o[0] | ((unsigned int)o[1] << 16);
    ov.y = (unsigned int)o[2] | ((unsigned int)o[3] << 16);
    ov.z = (unsigned int)o[4] | ((unsigned int)o[5] << 16);
    ov.w = (unsigned int)o[6] | ((unsigned int)o[7] << 16);
    *(uint4*)(outp + ((size_t)c * N_NODES + i) * 8) = ov;
}

// per node -> block-local LDS reduction by graph -> <=64 global atomics per block
__global__ __launch_bounds__(256) void k_pool(const float* __restrict__ dinv,
                                              const unsigned short* __restrict__ accb, // [13][N][8]
                                              const float* __restrict__ Wlin,
                                              const int* __restrict__ batch,
                                              float* __restrict__ pool,
                                              float* __restrict__ cnt) {
    __shared__ float sp[N_GRAPHS];
    __shared__ float sc[N_GRAPHS];
    const int t = threadIdx.x;
    if (t < N_GRAPHS) { sp[t] = 0.0f; sc[t] = 0.0f; }
    __syncthreads();
    int i = blockIdx.x * blockDim.x + t;
    if (i < N_NODES) {
        float di = dinv[i];
        float s = 0.0f;
#pragma unroll
        for (int c = 0; c < 13; ++c) {
            uint4 v = *(const uint4*)(accb + ((size_t)c * N_NODES + i) * 8);
            float e0 = b2f(v.x & 0xffff), e1 = b2f(v.x >> 16);
            float e2 = b2f(v.y & 0xffff), e3 = b2f(v.y >> 16);
            float e4 = b2f(v.z & 0xffff), e5 = b2f(v.z >> 16);
            float e6 = b2f(v.w & 0xffff), e7 = b2f(v.w >> 16);
            if (c < 12) {
                s += e0 * Wlin[8 * c + 0] + e1 * Wlin[8 * c + 1]
                   + e2 * Wlin[8 * c + 2] + e3 * Wlin[8 * c + 3]
                   + e4 * Wlin[8 * c + 4] + e5 * Wlin[8 * c + 5]
                   + e6 * Wlin[8 * c + 6] + e7 * Wlin[8 * c + 7];
            } else {
                s += e0 * Wlin[96] + e1 * Wlin[97] + e2 * Wlin[98] + e3 * Wlin[99];
            }
        }
        s *= di;
        int g = batch[i];
        atomicAdd(&sp[g], s);
        atomicAdd(&sc[g], 1.0f);
    }
    __syncthreads();
    if (t < N_GRAPHS && sc[t] != 0.0f) {
        atomicAdd(&pool[t], sp[t]);
        atomicAdd(&cnt[t], sc[t]);
    }
}

__global__ void k_final(const float* __restrict__ pool, const float* __restrict__ cnt,
                        const float* __restrict__ b2, const float* __restrict__ Wlin,
                        const float* __restrict__ blin, float* __restrict__ out) {
    int g = threadIdx.x;
    if (g >= N_GRAPHS) return;
    float c2 = 0.0f;
    for (int j = 0; j < HID; ++j) c2 += b2[j] * Wlin[j];
    out[g] = pool[g] / fmaxf(cnt[g], 1.0f) + c2 + blin[0];
}

extern "C" void kernel_launch(void* const* d_in, const int* in_sizes, int n_in,
                              void* d_out, int out_size, void* d_ws, size_t ws_size,
                              hipStream_t stream) {
    const float* x    = (const float*)d_in[0];
    const int*   ei   = (const int*)d_in[1];
    const int*   batch= (const int*)d_in[2];
    const float* W1   = (const float*)d_in[3];
    const float* b1   = (const float*)d_in[4];
    const float* W2   = (const float*)d_in[5];
    const float* b2   = (const float*)d_in[6];
    const float* Wlin = (const float*)d_in[7];
    const float* blin = (const float*)d_in[8];
    float* out = (float*)d_out;

    const int E = in_sizes[1] / 2;
    const int* src = ei;
    const int* dst = ei + E;

    float* wsf  = (float*)d_ws;
    int*   wsi  = (int*)d_ws;
    float* dinv = wsf + OFF_DINV;
    float* cntf = wsf + OFF_CNTF;
    float* pool = wsf + OFF_POOL;
    unsigned short* Wt1 = (unsigned short*)(wsf + OFF_WT1);
    unsigned short* Wt2 = (unsigned short*)(wsf + OFF_WT2);
    unsigned short* HS  = (unsigned short*)(wsf + OFF_HS);
    unsigned short* H1  = (unsigned short*)(wsf + OFF_H1);
    unsigned short* ACC = (unsigned short*)(wsf + OFF_ACC);
    int* rowptr = wsi + OFF_ROWPTR;
    unsigned short* eidx = (unsigned short*)(wsi + OFF_EIDX);
    unsigned int* bE = (unsigned int*)(wsi + OFF_BE);
    int* bbins  = wsi + OFF_BBINS;
    int* boff   = wsi + OFF_BOFF;
    int* btot   = wsi + OFF_BTOT;
    int* bbase  = wsi + OFF_BBASE;

    const int nbE = (E + BKE - 1) / BKE;   // 196 for E=800k (<= MAXBLK)
    const int gatherGrid = 8 * NSUB2;      // 3128

    // CSR build (two-level counting sort) + dinv + weight transposes
    k_zero<<<1, 128, 0, stream>>>(pool, cntf);
    k_wt<<<56, 256, 0, stream>>>(W1, 128, Wt1);
    k_wt<<<56, 256, 0, stream>>>(W2, 100, Wt2);
    k_p1<<<nbE, 256, 0, stream>>>(dst, E, bbins);
    k_p2a<<<NBIN, 256, 0, stream>>>(bbins, nbE, boff, btot);
    k_p2b<<<1, 256, 0, stream>>>(btot, E, bbase, rowptr);
    k_p3<<<nbE, 256, 0, stream>>>(src, dst, E, boff, bbase, bE);
    k_p4<<<NBIN, 256, 0, stream>>>(bE, bbase, rowptr, eidx, dinv);

    // layer 1
    k_gemm<false><<<(N_NODES + 63) / 64, 256, 0, stream>>>(x, Wt1, dinv, HS);
    k_gather<true><<<gatherGrid, 256, 0, stream>>>(rowptr, eidx, HS, dinv, b1, H1);

    // layer 2
    k_gemm<true><<<(N_NODES + 63) / 64, 256, 0, stream>>>(H1, Wt2, dinv, HS);
    k_gather<false><<<gatherGrid, 256, 0, stream>>>(rowptr, eidx, HS, dinv, b1, ACC);

    // readout
    k_pool<<<(N_NODES + 255) / 256, 256, 0, stream>>>(dinv, ACC, Wlin, batch, pool, cntf);
    k_final<<<1, 64, 0, stream>>>(pool, cntf, b2, Wlin, blin, out);
}

// Round 10
// 162.570 us; speedup vs baseline: 1.3269x; 1.3269x over previous
//
#include <hip/hip_runtime.h>
#include <hip/hip_bf16.h>

#define N_NODES 50000
#define N_GRAPHS 64
#define HID 100
#define HP 104            // padded bf16 row stride (13 * 8)

#define BKE  4096         // edges per block in p1/p3
#define NBIN 196          // buckets of 256 nodes: ceil(50000/256)
#define MAXBLK 256        // max edge-blocks supported (E <= 1M)

// ---- workspace layout (float offsets) ----
// HS/H1 are ROW-MAJOR bf16 [N][104] (round-9 chunk-major lost L1 row-sharing: reverted)
#define OFF_DINV 0
#define OFF_CNTF 50048
#define OFF_POOL 50112
#define OFF_WT1  50176                    // bf16 [112][128] = 7168 floats
#define OFF_WT2  57344
#define OFF_HS   64512                    // 2.6M floats
#define OFF_H1   2664512
#define OFF_ROWPTR 7864512                // N+1 ints
#define OFF_EIDX   7914560                // E ushorts
#define OFF_BE     8714560                // E uints (packed (src<<16)|dst, bucketed)
#define OFF_BBINS  9514560                // [MAXBLK][NBIN] ints
#define OFF_BOFF   9565760                // [MAXBLK][NBIN] ints
#define OFF_BTOT   9616960                // NBIN ints
#define OFF_BBASE  9617216                // NBIN+1 ints

typedef __attribute__((ext_vector_type(8))) short short8;
typedef __attribute__((ext_vector_type(4))) float floatx4;

__device__ inline float b2f(unsigned int u) {
    union { unsigned int v; float f; } x; x.v = u << 16; return x.f;
}
__device__ inline unsigned short f2b(float f) {
    union { float f; unsigned int v; } x; x.f = f;
    unsigned int r = (x.v + 0x7fffu + ((x.v >> 16) & 1u)) >> 16;   // RTNE
    return (unsigned short)r;
}

__global__ void k_zero(float* __restrict__ pool, float* __restrict__ cntf) {
    int i = threadIdx.x;
    if (i < N_GRAPHS) { pool[i] = 0.0f; cntf[i] = 0.0f; }
}

// W [KSRC][100] f32 -> Wt [112][128] bf16 (transposed, zero-padded)
__global__ void k_wt(const float* __restrict__ W, int KSRC, unsigned short* __restrict__ Wt) {
    int idx = blockIdx.x * 256 + threadIdx.x;
    if (idx >= 112 * 128) return;
    int c = idx >> 7, k = idx & 127;
    float v = (k < KSRC && c < HID) ? W[k * HID + c] : 0.0f;
    Wt[c * 128 + k] = f2b(v);
}

// ---- CSR build: two-level counting sort ----
__global__ __launch_bounds__(256) void k_p1(const int* __restrict__ dst, int E,
                                            int* __restrict__ bbins) {
    __shared__ int hist[256];
    const int t = threadIdx.x, b = blockIdx.x;
    hist[t] = 0;
    __syncthreads();
    int e0 = b * BKE, e1 = min(e0 + BKE, E);
    for (int e = e0 + t; e < e1; e += 256) atomicAdd(&hist[dst[e] >> 8], 1);
    __syncthreads();
    if (t < NBIN) bbins[b * NBIN + t] = hist[t];
}

__global__ __launch_bounds__(256) void k_p2a(const int* __restrict__ bbins, int nb,
                                             int* __restrict__ boff, int* __restrict__ btot) {
    __shared__ int sb[256];
    const int t = threadIdx.x, j = blockIdx.x;
    int v = (t < nb) ? bbins[t * NBIN + j] : 0;
    sb[t] = v;
    __syncthreads();
    for (int off = 1; off < 256; off <<= 1) {
        int u = (t >= off) ? sb[t - off] : 0;
        __syncthreads();
        sb[t] += u;
        __syncthreads();
    }
    if (t < nb) boff[t * NBIN + j] = sb[t] - v;
    if (t == 255) btot[j] = sb[255];
}

__global__ __launch_bounds__(256) void k_p2b(const int* __restrict__ btot, int E,
                                             int* __restrict__ bbase, int* __restrict__ rowptr) {
    __shared__ int sb[256];
    const int t = threadIdx.x;
    int v = (t < NBIN) ? btot[t] : 0;
    sb[t] = v;
    __syncthreads();
    for (int off = 1; off < 256; off <<= 1) {
        int u = (t >= off) ? sb[t - off] : 0;
        __syncthreads();
        sb[t] += u;
        __syncthreads();
    }
    if (t < NBIN) bbase[t] = sb[t] - v;
    if (t == 0) { bbase[NBIN] = E; rowptr[N_NODES] = E; }
}

__global__ __launch_bounds__(256) void k_p3(const int* __restrict__ src, const int* __restrict__ dst,
                                            int E, const int* __restrict__ boff,
                                            const int* __restrict__ bbase,
                                            unsigned int* __restrict__ bE) {
    __shared__ unsigned int stage[BKE];
    __shared__ int hist[256], pref[256], cur[256], sb[256], offr[NBIN];
    const int t = threadIdx.x, b = blockIdx.x;
    hist[t] = 0;
    if (t < NBIN) offr[t] = boff[b * NBIN + t] + bbase[t];
    __syncthreads();
    int e0 = b * BKE, e1 = min(e0 + BKE, E), n = e1 - e0;
    unsigned int mine[BKE / 256];
    int cnt = 0;
    for (int e = e0 + t; e < e1; e += 256) {
        unsigned int v = ((unsigned int)src[e] << 16) | (unsigned int)dst[e];
        mine[cnt++] = v;
        atomicAdd(&hist[(v >> 8) & 255], 1);
    }
    __syncthreads();
    sb[t] = hist[t];
    __syncthreads();
    for (int off = 1; off < 256; off <<= 1) {
        int v = (t >= off) ? sb[t - off] : 0;
        __syncthreads();
        sb[t] += v;
        __syncthreads();
    }
    pref[t] = sb[t] - hist[t];
    cur[t] = pref[t];
    __syncthreads();
    for (int c = 0; c < cnt; ++c) {
        unsigned int v = mine[c];
        int p = atomicAdd(&cur[(v >> 8) & 255], 1);
        stage[p] = v;
    }
    __syncthreads();
    for (int i = t; i < n; i += 256) {
        unsigned int v = stage[i];
        int bin = (v >> 8) & 255;
        bE[offr[bin] + (i - pref[bin])] = v;
    }
}

// p4: per-bucket sort by node -> rowptr, dinv, eidx (uint16 src ids)
__global__ __launch_bounds__(256) void k_p4(const unsigned int* __restrict__ bE,
                                            const int* __restrict__ bbase,
                                            int* __restrict__ rowptr, unsigned short* __restrict__ eidx,
                                            float* __restrict__ dinv) {
    __shared__ int hist[256], pref[256], cur[256], sb[256];
    const int t = threadIdx.x, b = blockIdx.x;
    const int eBase = bbase[b], eEnd = bbase[b + 1], n = eEnd - eBase;
    hist[t] = 0;
    __syncthreads();
    for (int i = t; i < n; i += 256) atomicAdd(&hist[bE[eBase + i] & 255], 1);
    __syncthreads();
    sb[t] = hist[t];
    __syncthreads();
    for (int off = 1; off < 256; off <<= 1) {
        int v = (t >= off) ? sb[t - off] : 0;
        __syncthreads();
        sb[t] += v;
        __syncthreads();
    }
    pref[t] = sb[t] - hist[t];
    cur[t] = pref[t];
    int node = (b << 8) + t;
    if (node < N_NODES) {
        rowptr[node] = eBase + pref[t];
        dinv[node] = rsqrtf((float)(hist[t] + 1));   // +1 self loop
    }
    __syncthreads();
    for (int i = t; i < n; i += 256) {
        unsigned int v = bE[eBase + i];
        int p = atomicAdd(&cur[v & 255], 1);
        eidx[eBase + p] = (unsigned short)(v >> 16);
    }
}

// MFMA bf16 GEMM: out[i][c] = f2b(dinv[i] * sum_k A[i][k] * W[k][c]), out [N][HP] bf16.
template<bool ABF16>
__global__ __launch_bounds__(256) void k_gemm(const void* __restrict__ Asrc,
                                              const unsigned short* __restrict__ Wt, // [112][128]
                                              const float* __restrict__ dinv,
                                              unsigned short* __restrict__ out) {
    __shared__ __align__(16) unsigned short xs[64][136];
    __shared__ __align__(16) unsigned short ws[112][136];
    const int t = threadIdx.x;
    const int base = blockIdx.x * 64;

    for (int idx = t; idx < 112 * 64; idx += 256) {
        int c = idx >> 6, u = idx & 63;
        *(unsigned int*)&ws[c][2 * u] = ((const unsigned int*)Wt)[idx];
    }
    if (ABF16) {
        const unsigned short* A = (const unsigned short*)Asrc;   // [N][HP] bf16
        for (int idx = t; idx < 64 * 16; idx += 256) {
            int r = idx >> 4, q = idx & 15;
            int row = base + r;
            uint4 v = make_uint4(0, 0, 0, 0);
            if (q < 13 && row < N_NODES)
                v = ((const uint4*)(A + (size_t)row * HP))[q];
            *(uint4*)&xs[r][8 * q] = v;
        }
    } else {
        const float* A = (const float*)Asrc;                     // [N][128] f32
        for (int idx = t; idx < 64 * 32; idx += 256) {
            int r = idx >> 5, q = idx & 31;
            int row = base + r;
            ushort4 p;
            if (row < N_NODES) {
                float4 v = ((const float4*)(A + (size_t)row * 128))[q];
                p.x = f2b(v.x); p.y = f2b(v.y); p.z = f2b(v.z); p.w = f2b(v.w);
            } else p = make_ushort4(0, 0, 0, 0);
            *(ushort4*)&xs[r][4 * q] = p;
        }
    }
    __syncthreads();

    const int lane = t & 63, w = t >> 6;
    const int g = lane >> 4, cl = lane & 15;

    floatx4 acc[7];
#pragma unroll
    for (int n = 0; n < 7; ++n) acc[n] = (floatx4){0.f, 0.f, 0.f, 0.f};

#pragma unroll
    for (int kc = 0; kc < 4; ++kc) {
        short8 a = *(const short8*)&xs[w * 16 + cl][kc * 32 + 8 * g];
#pragma unroll
        for (int n = 0; n < 7; ++n) {
            short8 b = *(const short8*)&ws[n * 16 + cl][kc * 32 + 8 * g];
            acc[n] = __builtin_amdgcn_mfma_f32_16x16x32_bf16(a, b, acc[n], 0, 0, 0);
        }
    }

    float di[4]; int grows[4];
#pragma unroll
    for (int r = 0; r < 4; ++r) {
        grows[r] = base + w * 16 + 4 * g + r;
        di[r] = (grows[r] < N_NODES) ? dinv[grows[r]] : 0.0f;
    }
#pragma unroll
    for (int n = 0; n < 7; ++n) {
        int gcol = n * 16 + cl;
        if (gcol >= HP) continue;
#pragma unroll
        for (int r = 0; r < 4; ++r) {
            if (grows[r] < N_NODES)
                out[(size_t)grows[r] * HP + gcol] = f2b(acc[n][r] * di[r]);
        }
    }
}

#define ACC8(v) do { \
    s[0] += b2f((v).x & 0xffff); s[1] += b2f((v).x >> 16); \
    s[2] += b2f((v).y & 0xffff); s[3] += b2f((v).y >> 16); \
    s[4] += b2f((v).z & 0xffff); s[5] += b2f((v).z >> 16); \
    s[6] += b2f((v).w & 0xffff); s[7] += b2f((v).w >> 16); } while (0)

// gather: thread = (node, 8-col chunk), 13/node (row-major: 13 threads share src row in L1).
// 8-deep edge unroll -> 8 independent loads in flight (round-8 loop had ~1).
// FIN1: h1 = tanh(dinv*(self+sum)+b1). Else: fused pool (dot Wlin, two-level atomic reduce).
template<bool FIN1>
__global__ __launch_bounds__(256) void k_gather(const int* __restrict__ rowptr,
                                                const unsigned short* __restrict__ eidx,
                                                const unsigned short* __restrict__ hs,
                                                const float* __restrict__ dinv,
                                                const float* __restrict__ b1,
                                                unsigned short* __restrict__ h1,
                                                const float* __restrict__ Wlin,
                                                const int* __restrict__ batch,
                                                float* __restrict__ pool,
                                                float* __restrict__ cntf) {
    __shared__ float sp[N_GRAPHS];
    __shared__ float sc[N_GRAPHS];
    const int t = threadIdx.x;
    if (!FIN1) {
        if (t < N_GRAPHS) { sp[t] = 0.0f; sc[t] = 0.0f; }
        __syncthreads();
    }
    const int w = blockIdx.x * 256 + t;
    const bool active = (w < N_NODES * 13);
    int i = 0, c = 0;
    float s[8] = {0.f, 0.f, 0.f, 0.f, 0.f, 0.f, 0.f, 0.f};
    if (active) {
        i = w / 13; c = w % 13;
        const int c0 = 8 * c;
        uint4 sv = *(const uint4*)(hs + (size_t)i * HP + c0);   // self loop
        ACC8(sv);
        int e = rowptr[i];
        const int end = rowptr[i + 1];
        for (; e + 8 <= end; e += 8) {
            int n0 = eidx[e],     n1 = eidx[e + 1], n2 = eidx[e + 2], n3 = eidx[e + 3];
            int n4 = eidx[e + 4], n5 = eidx[e + 5], n6 = eidx[e + 6], n7 = eidx[e + 7];
            uint4 v0 = *(const uint4*)(hs + (size_t)n0 * HP + c0);
            uint4 v1 = *(const uint4*)(hs + (size_t)n1 * HP + c0);
            uint4 v2 = *(const uint4*)(hs + (size_t)n2 * HP + c0);
            uint4 v3 = *(const uint4*)(hs + (size_t)n3 * HP + c0);
            uint4 v4 = *(const uint4*)(hs + (size_t)n4 * HP + c0);
            uint4 v5 = *(const uint4*)(hs + (size_t)n5 * HP + c0);
            uint4 v6 = *(const uint4*)(hs + (size_t)n6 * HP + c0);
            uint4 v7 = *(const uint4*)(hs + (size_t)n7 * HP + c0);
            ACC8(v0); ACC8(v1); ACC8(v2); ACC8(v3);
            ACC8(v4); ACC8(v5); ACC8(v6); ACC8(v7);
        }
        for (; e + 4 <= end; e += 4) {
            int n0 = eidx[e], n1 = eidx[e + 1], n2 = eidx[e + 2], n3 = eidx[e + 3];
            uint4 v0 = *(const uint4*)(hs + (size_t)n0 * HP + c0);
            uint4 v1 = *(const uint4*)(hs + (size_t)n1 * HP + c0);
            uint4 v2 = *(const uint4*)(hs + (size_t)n2 * HP + c0);
            uint4 v3 = *(const uint4*)(hs + (size_t)n3 * HP + c0);
            ACC8(v0); ACC8(v1); ACC8(v2); ACC8(v3);
        }
        for (; e < end; ++e) {
            uint4 v = *(const uint4*)(hs + (size_t)eidx[e] * HP + c0);
            ACC8(v);
        }
    }

    if (FIN1) {
        if (active) {
            const int c0 = 8 * c;
            float di = dinv[i];
            unsigned short o[8];
            if (c < 12) {
#pragma unroll
                for (int j = 0; j < 8; ++j) o[j] = f2b(tanhf(di * s[j] + b1[c0 + j]));
            } else {
#pragma unroll
                for (int j = 0; j < 4; ++j) o[j] = f2b(tanhf(di * s[j] + b1[96 + j]));
#pragma unroll
                for (int j = 4; j < 8; ++j) o[j] = 0;   // pad cols must stay 0
            }
            uint4 ov;
            ov.x = (unsigned int)o[0] | ((unsigned int)o[1] << 16);
            ov.y = (unsigned int)o[2] | ((unsigned int)o[3] << 16);
            ov.z = (unsigned int)o[4] | ((unsigned int)o[5] << 16);
            ov.w = (unsigned int)o[6] | ((unsigned int)o[7] << 16);
            *(uint4*)(h1 + (size_t)i * HP + c0) = ov;
        }
    } else {
        if (active) {
            const int c0 = 8 * c;
            float p;
            if (c < 12) {
                p = s[0] * Wlin[c0 + 0] + s[1] * Wlin[c0 + 1]
                  + s[2] * Wlin[c0 + 2] + s[3] * Wlin[c0 + 3]
                  + s[4] * Wlin[c0 + 4] + s[5] * Wlin[c0 + 5]
                  + s[6] * Wlin[c0 + 6] + s[7] * Wlin[c0 + 7];
            } else {
                p = s[0] * Wlin[96] + s[1] * Wlin[97] + s[2] * Wlin[98] + s[3] * Wlin[99];
            }
            p *= dinv[i];
            int g = batch[i];
            atomicAdd(&sp[g], p);
            if (c == 0) atomicAdd(&sc[g], 1.0f);
        }
        __syncthreads();
        if (t < N_GRAPHS && (sp[t] != 0.0f || sc[t] != 0.0f)) {
            atomicAdd(&pool[t], sp[t]);
            atomicAdd(&cntf[t], sc[t]);
        }
    }
}

__global__ void k_final(const float* __restrict__ pool, const float* __restrict__ cnt,
                        const float* __restrict__ b2, const float* __restrict__ Wlin,
                        const float* __restrict__ blin, float* __restrict__ out) {
    int g = threadIdx.x;
    if (g >= N_GRAPHS) return;
    float c2 = 0.0f;
    for (int j = 0; j < HID; ++j) c2 += b2[j] * Wlin[j];
    out[g] = pool[g] / fmaxf(cnt[g], 1.0f) + c2 + blin[0];
}

extern "C" void kernel_launch(void* const* d_in, const int* in_sizes, int n_in,
                              void* d_out, int out_size, void* d_ws, size_t ws_size,
                              hipStream_t stream) {
    const float* x    = (const float*)d_in[0];
    const int*   ei   = (const int*)d_in[1];
    const int*   batch= (const int*)d_in[2];
    const float* W1   = (const float*)d_in[3];
    const float* b1   = (const float*)d_in[4];
    const float* W2   = (const float*)d_in[5];
    const float* b2   = (const float*)d_in[6];
    const float* Wlin = (const float*)d_in[7];
    const float* blin = (const float*)d_in[8];
    float* out = (float*)d_out;

    const int E = in_sizes[1] / 2;
    const int* src = ei;
    const int* dst = ei + E;

    float* wsf  = (float*)d_ws;
    int*   wsi  = (int*)d_ws;
    float* dinv = wsf + OFF_DINV;
    float* cntf = wsf + OFF_CNTF;
    float* pool = wsf + OFF_POOL;
    unsigned short* Wt1 = (unsigned short*)(wsf + OFF_WT1);
    unsigned short* Wt2 = (unsigned short*)(wsf + OFF_WT2);
    unsigned short* HS  = (unsigned short*)(wsf + OFF_HS);
    unsigned short* H1  = (unsigned short*)(wsf + OFF_H1);
    int* rowptr = wsi + OFF_ROWPTR;
    unsigned short* eidx = (unsigned short*)(wsi + OFF_EIDX);
    unsigned int* bE = (unsigned int*)(wsi + OFF_BE);
    int* bbins  = wsi + OFF_BBINS;
    int* boff   = wsi + OFF_BOFF;
    int* btot   = wsi + OFF_BTOT;
    int* bbase  = wsi + OFF_BBASE;

    const int nbE = (E + BKE - 1) / BKE;   // 196 for E=800k (<= MAXBLK)
    const int gGrid = (N_NODES * 13 + 255) / 256;

    // CSR build (two-level counting sort) + dinv + weight transposes
    k_zero<<<1, 128, 0, stream>>>(pool, cntf);
    k_wt<<<56, 256, 0, stream>>>(W1, 128, Wt1);
    k_wt<<<56, 256, 0, stream>>>(W2, 100, Wt2);
    k_p1<<<nbE, 256, 0, stream>>>(dst, E, bbins);
    k_p2a<<<NBIN, 256, 0, stream>>>(bbins, nbE, boff, btot);
    k_p2b<<<1, 256, 0, stream>>>(btot, E, bbase, rowptr);
    k_p3<<<nbE, 256, 0, stream>>>(src, dst, E, boff, bbase, bE);
    k_p4<<<NBIN, 256, 0, stream>>>(bE, bbase, rowptr, eidx, dinv);

    // layer 1
    k_gemm<false><<<(N_NODES + 63) / 64, 256, 0, stream>>>(x, Wt1, dinv, HS);
    k_gather<true><<<gGrid, 256, 0, stream>>>(rowptr, eidx, HS, dinv, b1, H1,
                                              Wlin, batch, pool, cntf);

    // layer 2 (+ fused pool)
    k_gemm<true><<<(N_NODES + 63) / 64, 256, 0, stream>>>(H1, Wt2, dinv, HS);
    k_gather<false><<<gGrid, 256, 0, stream>>>(rowptr, eidx, HS, dinv, b1, nullptr,
                                               Wlin, batch, pool, cntf);

    // readout
    k_final<<<1, 64, 0, stream>>>(pool, cntf, b2, Wlin, blin, out);
}

// Round 11
// 118.714 us; speedup vs baseline: 1.8171x; 1.3694x over previous
//
#include <hip/hip_runtime.h>
#include <hip/hip_bf16.h>

#define N_NODES 50000
#define N_GRAPHS 64
#define HID 100
#define HP 104            // padded bf16 row stride (13 * 8)

#define BKE  4096         // edges per block in p1/p3
#define NBIN 196          // buckets of 256 nodes: ceil(50000/256)
#define MAXBLK 256        // max edge-blocks supported (E <= 1M)

// ---- workspace layout (float offsets) ----
// HS/H1 row-major bf16 [N][104]
#define OFF_DINV 0
#define OFF_CNTF 50048
#define OFF_POOL 50112
#define OFF_WT1  50176                    // bf16 [112][128] = 7168 floats
#define OFF_HS   64512                    // 2.6M floats
#define OFF_H1   2664512
#define OFF_ROWPTR 7864512                // N+1 ints
#define OFF_EIDX   7914560                // E ushorts
#define OFF_BE     8714560                // E uints (packed (src<<16)|dst, bucketed)
#define OFF_BBINS  9514560                // [MAXBLK][NBIN] ints
#define OFF_BOFF   9565760                // [MAXBLK][NBIN] ints
#define OFF_BTOT   9616960                // NBIN ints
#define OFF_BBASE  9617216                // NBIN+1 ints
#define OFF_W2L    9617472                // 106 floats: w2l[0..103] (pad 0), [104]=b2.Wlin
#define OFF_Q      9617600                // N floats
// end ~9,667,648 floats = 38.7 MB

typedef __attribute__((ext_vector_type(8))) short short8;
typedef __attribute__((ext_vector_type(4))) float floatx4;

__device__ inline float b2f(unsigned int u) {
    union { unsigned int v; float f; } x; x.v = u << 16; return x.f;
}
__device__ inline unsigned short f2b(float f) {
    union { float f; unsigned int v; } x; x.f = f;
    unsigned int r = (x.v + 0x7fffu + ((x.v >> 16) & 1u)) >> 16;   // RTNE
    return (unsigned short)r;
}

__global__ void k_zero(float* __restrict__ pool, float* __restrict__ cntf) {
    int i = threadIdx.x;
    if (i < N_GRAPHS) { pool[i] = 0.0f; cntf[i] = 0.0f; }
}

// W [KSRC][100] f32 -> Wt [112][128] bf16 (transposed, zero-padded)
__global__ void k_wt(const float* __restrict__ W, int KSRC, unsigned short* __restrict__ Wt) {
    int idx = blockIdx.x * 256 + threadIdx.x;
    if (idx >= 112 * 128) return;
    int c = idx >> 7, k = idx & 127;
    float v = (k < KSRC && c < HID) ? W[k * HID + c] : 0.0f;
    Wt[c * 128 + k] = f2b(v);
}

// w2l[k] = sum_c W2[k][c]*Wlin[c] (k<100; pad 0 for 100..103); w2l[104] = b2.Wlin
// (layer-2 GEMM collapses: q = dinv * (H1 @ w2l) since post-conv2 path is linear)
__global__ void k_w2l(const float* __restrict__ W2, const float* __restrict__ Wlin,
                      const float* __restrict__ b2, float* __restrict__ w2l) {
    int t = threadIdx.x;
    if (t < 104) {
        float s = 0.0f;
        if (t < 100)
            for (int c = 0; c < HID; ++c) s += W2[t * HID + c] * Wlin[c];
        w2l[t] = s;
    } else if (t == 104) {
        float s = 0.0f;
        for (int j = 0; j < HID; ++j) s += b2[j] * Wlin[j];
        w2l[104] = s;
    }
}

// ---- CSR build: two-level counting sort ----
__global__ __launch_bounds__(256) void k_p1(const int* __restrict__ dst, int E,
                                            int* __restrict__ bbins) {
    __shared__ int hist[256];
    const int t = threadIdx.x, b = blockIdx.x;
    hist[t] = 0;
    __syncthreads();
    int e0 = b * BKE, e1 = min(e0 + BKE, E);
    for (int e = e0 + t; e < e1; e += 256) atomicAdd(&hist[dst[e] >> 8], 1);
    __syncthreads();
    if (t < NBIN) bbins[b * NBIN + t] = hist[t];
}

__global__ __launch_bounds__(256) void k_p2a(const int* __restrict__ bbins, int nb,
                                             int* __restrict__ boff, int* __restrict__ btot) {
    __shared__ int sb[256];
    const int t = threadIdx.x, j = blockIdx.x;
    int v = (t < nb) ? bbins[t * NBIN + j] : 0;
    sb[t] = v;
    __syncthreads();
    for (int off = 1; off < 256; off <<= 1) {
        int u = (t >= off) ? sb[t - off] : 0;
        __syncthreads();
        sb[t] += u;
        __syncthreads();
    }
    if (t < nb) boff[t * NBIN + j] = sb[t] - v;
    if (t == 255) btot[j] = sb[255];
}

__global__ __launch_bounds__(256) void k_p2b(const int* __restrict__ btot, int E,
                                             int* __restrict__ bbase, int* __restrict__ rowptr) {
    __shared__ int sb[256];
    const int t = threadIdx.x;
    int v = (t < NBIN) ? btot[t] : 0;
    sb[t] = v;
    __syncthreads();
    for (int off = 1; off < 256; off <<= 1) {
        int u = (t >= off) ? sb[t - off] : 0;
        __syncthreads();
        sb[t] += u;
        __syncthreads();
    }
    if (t < NBIN) bbase[t] = sb[t] - v;
    if (t == 0) { bbase[NBIN] = E; rowptr[N_NODES] = E; }
}

__global__ __launch_bounds__(256) void k_p3(const int* __restrict__ src, const int* __restrict__ dst,
                                            int E, const int* __restrict__ boff,
                                            const int* __restrict__ bbase,
                                            unsigned int* __restrict__ bE) {
    __shared__ unsigned int stage[BKE];
    __shared__ int hist[256], pref[256], cur[256], sb[256], offr[NBIN];
    const int t = threadIdx.x, b = blockIdx.x;
    hist[t] = 0;
    if (t < NBIN) offr[t] = boff[b * NBIN + t] + bbase[t];
    __syncthreads();
    int e0 = b * BKE, e1 = min(e0 + BKE, E), n = e1 - e0;
    unsigned int mine[BKE / 256];
    int cnt = 0;
    for (int e = e0 + t; e < e1; e += 256) {
        unsigned int v = ((unsigned int)src[e] << 16) | (unsigned int)dst[e];
        mine[cnt++] = v;
        atomicAdd(&hist[(v >> 8) & 255], 1);
    }
    __syncthreads();
    sb[t] = hist[t];
    __syncthreads();
    for (int off = 1; off < 256; off <<= 1) {
        int v = (t >= off) ? sb[t - off] : 0;
        __syncthreads();
        sb[t] += v;
        __syncthreads();
    }
    pref[t] = sb[t] - hist[t];
    cur[t] = pref[t];
    __syncthreads();
    for (int c = 0; c < cnt; ++c) {
        unsigned int v = mine[c];
        int p = atomicAdd(&cur[(v >> 8) & 255], 1);
        stage[p] = v;
    }
    __syncthreads();
    for (int i = t; i < n; i += 256) {
        unsigned int v = stage[i];
        int bin = (v >> 8) & 255;
        bE[offr[bin] + (i - pref[bin])] = v;
    }
}

// p4: per-bucket sort by node -> rowptr, dinv, eidx (uint16 src ids)
__global__ __launch_bounds__(256) void k_p4(const unsigned int* __restrict__ bE,
                                            const int* __restrict__ bbase,
                                            int* __restrict__ rowptr, unsigned short* __restrict__ eidx,
                                            float* __restrict__ dinv) {
    __shared__ int hist[256], pref[256], cur[256], sb[256];
    const int t = threadIdx.x, b = blockIdx.x;
    const int eBase = bbase[b], eEnd = bbase[b + 1], n = eEnd - eBase;
    hist[t] = 0;
    __syncthreads();
    for (int i = t; i < n; i += 256) atomicAdd(&hist[bE[eBase + i] & 255], 1);
    __syncthreads();
    sb[t] = hist[t];
    __syncthreads();
    for (int off = 1; off < 256; off <<= 1) {
        int v = (t >= off) ? sb[t - off] : 0;
        __syncthreads();
        sb[t] += v;
        __syncthreads();
    }
    pref[t] = sb[t] - hist[t];
    cur[t] = pref[t];
    int node = (b << 8) + t;
    if (node < N_NODES) {
        rowptr[node] = eBase + pref[t];
        dinv[node] = rsqrtf((float)(hist[t] + 1));   // +1 self loop
    }
    __syncthreads();
    for (int i = t; i < n; i += 256) {
        unsigned int v = bE[eBase + i];
        int p = atomicAdd(&cur[v & 255], 1);
        eidx[eBase + p] = (unsigned short)(v >> 16);
    }
}

// MFMA bf16 GEMM (layer 1 only): out[i][c] = f2b(dinv[i]*sum_k X[i][k]*W1[k][c]), [N][HP] bf16
__global__ __launch_bounds__(256) void k_gemm(const float* __restrict__ A,   // [N][128] f32
                                              const unsigned short* __restrict__ Wt, // [112][128]
                                              const float* __restrict__ dinv,
                                              unsigned short* __restrict__ out) {
    __shared__ __align__(16) unsigned short xs[64][136];
    __shared__ __align__(16) unsigned short ws[112][136];
    const int t = threadIdx.x;
    const int base = blockIdx.x * 64;

    for (int idx = t; idx < 112 * 64; idx += 256) {
        int c = idx >> 6, u = idx & 63;
        *(unsigned int*)&ws[c][2 * u] = ((const unsigned int*)Wt)[idx];
    }
    for (int idx = t; idx < 64 * 32; idx += 256) {
        int r = idx >> 5, q = idx & 31;
        int row = base + r;
        ushort4 p;
        if (row < N_NODES) {
            float4 v = ((const float4*)(A + (size_t)row * 128))[q];
            p.x = f2b(v.x); p.y = f2b(v.y); p.z = f2b(v.z); p.w = f2b(v.w);
        } else p = make_ushort4(0, 0, 0, 0);
        *(ushort4*)&xs[r][4 * q] = p;
    }
    __syncthreads();

    const int lane = t & 63, w = t >> 6;
    const int g = lane >> 4, cl = lane & 15;

    floatx4 acc[7];
#pragma unroll
    for (int n = 0; n < 7; ++n) acc[n] = (floatx4){0.f, 0.f, 0.f, 0.f};

#pragma unroll
    for (int kc = 0; kc < 4; ++kc) {
        short8 a = *(const short8*)&xs[w * 16 + cl][kc * 32 + 8 * g];
#pragma unroll
        for (int n = 0; n < 7; ++n) {
            short8 b = *(const short8*)&ws[n * 16 + cl][kc * 32 + 8 * g];
            acc[n] = __builtin_amdgcn_mfma_f32_16x16x32_bf16(a, b, acc[n], 0, 0, 0);
        }
    }

    float di[4]; int grows[4];
#pragma unroll
    for (int r = 0; r < 4; ++r) {
        grows[r] = base + w * 16 + 4 * g + r;
        di[r] = (grows[r] < N_NODES) ? dinv[grows[r]] : 0.0f;
    }
#pragma unroll
    for (int n = 0; n < 7; ++n) {
        int gcol = n * 16 + cl;
        if (gcol >= HP) continue;
#pragma unroll
        for (int r = 0; r < 4; ++r) {
            if (grows[r] < N_NODES)
                out[(size_t)grows[r] * HP + gcol] = f2b(acc[n][r] * di[r]);
        }
    }
}

#define ACC8(v) do { \
    s[0] += b2f((v).x & 0xffff); s[1] += b2f((v).x >> 16); \
    s[2] += b2f((v).y & 0xffff); s[3] += b2f((v).y >> 16); \
    s[4] += b2f((v).z & 0xffff); s[5] += b2f((v).z >> 16); \
    s[6] += b2f((v).w & 0xffff); s[7] += b2f((v).w >> 16); } while (0)

// layer-1 gather: thread = (node, 8-col chunk); h1 = tanh(dinv*(self+sum)+b1).
// 8-deep edge unroll -> 8 independent loads in flight.
__global__ __launch_bounds__(256) void k_gather(const int* __restrict__ rowptr,
                                                const unsigned short* __restrict__ eidx,
                                                const unsigned short* __restrict__ hs,
                                                const float* __restrict__ dinv,
                                                const float* __restrict__ b1,
                                                unsigned short* __restrict__ h1) {
    const int w = blockIdx.x * 256 + threadIdx.x;
    if (w >= N_NODES * 13) return;
    const int i = w / 13, c = w % 13;
    const int c0 = 8 * c;
    float s[8] = {0.f, 0.f, 0.f, 0.f, 0.f, 0.f, 0.f, 0.f};
    uint4 sv = *(const uint4*)(hs + (size_t)i * HP + c0);   // self loop
    ACC8(sv);
    int e = rowptr[i];
    const int end = rowptr[i + 1];
    for (; e + 8 <= end; e += 8) {
        int n0 = eidx[e],     n1 = eidx[e + 1], n2 = eidx[e + 2], n3 = eidx[e + 3];
        int n4 = eidx[e + 4], n5 = eidx[e + 5], n6 = eidx[e + 6], n7 = eidx[e + 7];
        uint4 v0 = *(const uint4*)(hs + (size_t)n0 * HP + c0);
        uint4 v1 = *(const uint4*)(hs + (size_t)n1 * HP + c0);
        uint4 v2 = *(const uint4*)(hs + (size_t)n2 * HP + c0);
        uint4 v3 = *(const uint4*)(hs + (size_t)n3 * HP + c0);
        uint4 v4 = *(const uint4*)(hs + (size_t)n4 * HP + c0);
        uint4 v5 = *(const uint4*)(hs + (size_t)n5 * HP + c0);
        uint4 v6 = *(const uint4*)(hs + (size_t)n6 * HP + c0);
        uint4 v7 = *(const uint4*)(hs + (size_t)n7 * HP + c0);
        ACC8(v0); ACC8(v1); ACC8(v2); ACC8(v3);
        ACC8(v4); ACC8(v5); ACC8(v6); ACC8(v7);
    }
    for (; e + 4 <= end; e += 4) {
        int n0 = eidx[e], n1 = eidx[e + 1], n2 = eidx[e + 2], n3 = eidx[e + 3];
        uint4 v0 = *(const uint4*)(hs + (size_t)n0 * HP + c0);
        uint4 v1 = *(const uint4*)(hs + (size_t)n1 * HP + c0);
        uint4 v2 = *(const uint4*)(hs + (size_t)n2 * HP + c0);
        uint4 v3 = *(const uint4*)(hs + (size_t)n3 * HP + c0);
        ACC8(v0); ACC8(v1); ACC8(v2); ACC8(v3);
    }
    for (; e < end; ++e) {
        uint4 v = *(const uint4*)(hs + (size_t)eidx[e] * HP + c0);
        ACC8(v);
    }

    float di = dinv[i];
    unsigned short o[8];
    if (c < 12) {
#pragma unroll
        for (int j = 0; j < 8; ++j) o[j] = f2b(tanhf(di * s[j] + b1[c0 + j]));
    } else {
#pragma unroll
        for (int j = 0; j < 4; ++j) o[j] = f2b(tanhf(di * s[j] + b1[96 + j]));
#pragma unroll
        for (int j = 4; j < 8; ++j) o[j] = 0;   // pad cols must stay 0
    }
    uint4 ov;
    ov.x = (unsigned int)o[0] | ((unsigned int)o[1] << 16);
    ov.y = (unsigned int)o[2] | ((unsigned int)o[3] << 16);
    ov.z = (unsigned int)o[4] | ((unsigned int)o[5] << 16);
    ov.w = (unsigned int)o[6] | ((unsigned int)o[7] << 16);
    *(uint4*)(h1 + (size_t)i * HP + c0) = ov;
}

// q[i] = dinv[i] * dot(H1[i], w2l)  (layer-2 matvec; pad cols of H1 are 0)
__global__ __launch_bounds__(256) void k_q(const unsigned short* __restrict__ h1,
                                           const float* __restrict__ dinv,
                                           const float* __restrict__ w2l,
                                           float* __restrict__ q) {
    __shared__ float wl[104];
    const int t = threadIdx.x;
    if (t < 104) wl[t] = w2l[t];
    __syncthreads();
    int i = blockIdx.x * 256 + t;
    if (i >= N_NODES) return;
    const unsigned short* row = h1 + (size_t)i * HP;
    float s = 0.0f;
#pragma unroll
    for (int cq = 0; cq < 13; ++cq) {
        uint4 v = *(const uint4*)(row + 8 * cq);
        s += b2f(v.x & 0xffff) * wl[8 * cq + 0] + b2f(v.x >> 16) * wl[8 * cq + 1]
           + b2f(v.y & 0xffff) * wl[8 * cq + 2] + b2f(v.y >> 16) * wl[8 * cq + 3]
           + b2f(v.z & 0xffff) * wl[8 * cq + 4] + b2f(v.z >> 16) * wl[8 * cq + 5]
           + b2f(v.w & 0xffff) * wl[8 * cq + 6] + b2f(v.w >> 16) * wl[8 * cq + 7];
    }
    q[i] = dinv[i] * s;
}

// fused layer-2 aggregate + mean-pool: scalar gather from 200KB q table
__global__ __launch_bounds__(256) void k_gpool(const int* __restrict__ rowptr,
                                               const unsigned short* __restrict__ eidx,
                                               const float* __restrict__ q,
                                               const float* __restrict__ dinv,
                                               const int* __restrict__ batch,
                                               float* __restrict__ pool,
                                               float* __restrict__ cntf) {
    __shared__ float sp[N_GRAPHS];
    __shared__ float sc[N_GRAPHS];
    const int t = threadIdx.x;
    if (t < N_GRAPHS) { sp[t] = 0.0f; sc[t] = 0.0f; }
    __syncthreads();
    int i = blockIdx.x * 256 + t;
    if (i < N_NODES) {
        float s = q[i];
        int e = rowptr[i];
        const int end = rowptr[i + 1];
        for (; e + 4 <= end; e += 4) {
            int n0 = eidx[e], n1 = eidx[e + 1], n2 = eidx[e + 2], n3 = eidx[e + 3];
            s += q[n0] + q[n1] + q[n2] + q[n3];
        }
        for (; e < end; ++e) s += q[eidx[e]];
        float p = dinv[i] * s;
        int g = batch[i];
        atomicAdd(&sp[g], p);
        atomicAdd(&sc[g], 1.0f);
    }
    __syncthreads();
    if (t < N_GRAPHS && sc[t] != 0.0f) {
        atomicAdd(&pool[t], sp[t]);
        atomicAdd(&cntf[t], sc[t]);
    }
}

__global__ void k_final(const float* __restrict__ pool, const float* __restrict__ cnt,
                        const float* __restrict__ w2l, const float* __restrict__ blin,
                        float* __restrict__ out) {
    int g = threadIdx.x;
    if (g >= N_GRAPHS) return;
    out[g] = pool[g] / fmaxf(cnt[g], 1.0f) + w2l[104] + blin[0];
}

extern "C" void kernel_launch(void* const* d_in, const int* in_sizes, int n_in,
                              void* d_out, int out_size, void* d_ws, size_t ws_size,
                              hipStream_t stream) {
    const float* x    = (const float*)d_in[0];
    const int*   ei   = (const int*)d_in[1];
    const int*   batch= (const int*)d_in[2];
    const float* W1   = (const float*)d_in[3];
    const float* b1   = (const float*)d_in[4];
    const float* W2   = (const float*)d_in[5];
    const float* b2   = (const float*)d_in[6];
    const float* Wlin = (const float*)d_in[7];
    const float* blin = (const float*)d_in[8];
    float* out = (float*)d_out;

    const int E = in_sizes[1] / 2;
    const int* src = ei;
    const int* dst = ei + E;

    float* wsf  = (float*)d_ws;
    int*   wsi  = (int*)d_ws;
    float* dinv = wsf + OFF_DINV;
    float* cntf = wsf + OFF_CNTF;
    float* pool = wsf + OFF_POOL;
    unsigned short* Wt1 = (unsigned short*)(wsf + OFF_WT1);
    unsigned short* HS  = (unsigned short*)(wsf + OFF_HS);
    unsigned short* H1  = (unsigned short*)(wsf + OFF_H1);
    int* rowptr = wsi + OFF_ROWPTR;
    unsigned short* eidx = (unsigned short*)(wsi + OFF_EIDX);
    unsigned int* bE = (unsigned int*)(wsi + OFF_BE);
    int* bbins  = wsi + OFF_BBINS;
    int* boff   = wsi + OFF_BOFF;
    int* btot   = wsi + OFF_BTOT;
    int* bbase  = wsi + OFF_BBASE;
    float* w2l  = wsf + OFF_W2L;
    float* q    = wsf + OFF_Q;

    const int nbE = (E + BKE - 1) / BKE;   // 196 for E=800k (<= MAXBLK)
    const int gGrid = (N_NODES * 13 + 255) / 256;
    const int nGrid = (N_NODES + 255) / 256;

    // CSR build (two-level counting sort) + dinv + weight prep
    k_zero<<<1, 128, 0, stream>>>(pool, cntf);
    k_wt<<<56, 256, 0, stream>>>(W1, 128, Wt1);
    k_w2l<<<1, 128, 0, stream>>>(W2, Wlin, b2, w2l);
    k_p1<<<nbE, 256, 0, stream>>>(dst, E, bbins);
    k_p2a<<<NBIN, 256, 0, stream>>>(bbins, nbE, boff, btot);
    k_p2b<<<1, 256, 0, stream>>>(btot, E, bbase, rowptr);
    k_p3<<<nbE, 256, 0, stream>>>(src, dst, E, boff, bbase, bE);
    k_p4<<<NBIN, 256, 0, stream>>>(bE, bbase, rowptr, eidx, dinv);

    // layer 1
    k_gemm<<<(N_NODES + 63) / 64, 256, 0, stream>>>(x, Wt1, dinv, HS);
    k_gather<<<gGrid, 256, 0, stream>>>(rowptr, eidx, HS, dinv, b1, H1);

    // layer 2 (collapsed to scalar matvec + scalar gather-pool)
    k_q<<<nGrid, 256, 0, stream>>>(H1, dinv, w2l, q);
    k_gpool<<<nGrid, 256, 0, stream>>>(rowptr, eidx, q, dinv, batch, pool, cntf);

    // readout
    k_final<<<1, 64, 0, stream>>>(pool, cntf, w2l, blin, out);
}

// Round 12
// 106.812 us; speedup vs baseline: 2.0196x; 1.1114x over previous
//
#include <hip/hip_runtime.h>
#include <hip/hip_bf16.h>

#define N_NODES 50000
#define N_GRAPHS 64
#define HID 100
#define HP 104            // padded bf16 row stride (13 * 8)

#define BKE  4096         // edges per block in p1/p3
#define NBIN 196          // buckets of 256 nodes: ceil(50000/256)
#define MAXBLK 256        // max edge-blocks supported (E <= 1M)

#define NPB 39            // nodes per gather block (39*13 = 507 of 512 threads)

// ---- workspace layout (float offsets) ----
// HS row-major bf16 [N][104]
#define OFF_DINV 0
#define OFF_CNTF 50048
#define OFF_POOL 50112
#define OFF_WT1  50176                    // bf16 [112][128] = 7168 floats
#define OFF_HS   64512                    // 2.6M floats
#define OFF_ROWPTR 7864512                // N+1 ints
#define OFF_EIDX   7914560                // E ushorts
#define OFF_BE     8714560                // E uints (packed (src<<16)|dst, bucketed)
#define OFF_BBINS  9514560                // [MAXBLK][NBIN] ints
#define OFF_BOFF   9565760                // [MAXBLK][NBIN] ints
#define OFF_BTOT   9616960                // NBIN ints
#define OFF_BBASE  9617216                // NBIN+1 ints
#define OFF_W2L    9617472                // 106 floats: w2l[0..103] (pad 0), [104]=b2.Wlin
#define OFF_Q      9617600                // N floats

typedef __attribute__((ext_vector_type(8))) short short8;
typedef __attribute__((ext_vector_type(4))) float floatx4;

__device__ inline float b2f(unsigned int u) {
    union { unsigned int v; float f; } x; x.v = u << 16; return x.f;
}
__device__ inline unsigned short f2b(float f) {
    union { float f; unsigned int v; } x; x.f = f;
    unsigned int r = (x.v + 0x7fffu + ((x.v >> 16) & 1u)) >> 16;   // RTNE
    return (unsigned short)r;
}

// prep: blocks 0..55 transpose W1 -> Wt1 bf16 [112][128]; block 56 zeroes pool/cnt
// and builds w2l[k]=sum_c W2[k][c]*Wlin[c] (+[104]=b2.Wlin)
__global__ __launch_bounds__(256) void k_prep(const float* __restrict__ W1,
                                              const float* __restrict__ W2,
                                              const float* __restrict__ Wlin,
                                              const float* __restrict__ b2,
                                              unsigned short* __restrict__ Wt1,
                                              float* __restrict__ w2l,
                                              float* __restrict__ pool,
                                              float* __restrict__ cntf) {
    const int b = blockIdx.x, t = threadIdx.x;
    if (b < 56) {
        int idx = b * 256 + t;
        int c = idx >> 7, k = idx & 127;
        float v = (k < 128 && c < HID) ? W1[k * HID + c] : 0.0f;
        Wt1[c * 128 + k] = f2b(v);
    } else {
        if (t < 104) {
            float s = 0.0f;
            if (t < 100)
                for (int c = 0; c < HID; ++c) s += W2[t * HID + c] * Wlin[c];
            w2l[t] = s;
        } else if (t == 104) {
            float s = 0.0f;
            for (int j = 0; j < HID; ++j) s += b2[j] * Wlin[j];
            w2l[104] = s;
        } else if (t >= 128 && t < 128 + N_GRAPHS) {
            pool[t - 128] = 0.0f; cntf[t - 128] = 0.0f;
        }
    }
}

// ---- CSR build: two-level counting sort ----
__global__ __launch_bounds__(256) void k_p1(const int* __restrict__ dst, int E,
                                            int* __restrict__ bbins) {
    __shared__ int hist[256];
    const int t = threadIdx.x, b = blockIdx.x;
    hist[t] = 0;
    __syncthreads();
    int e0 = b * BKE, e1 = min(e0 + BKE, E);
    for (int e = e0 + t; e < e1; e += 256) atomicAdd(&hist[dst[e] >> 8], 1);
    __syncthreads();
    if (t < NBIN) bbins[b * NBIN + t] = hist[t];
}

__global__ __launch_bounds__(256) void k_p2a(const int* __restrict__ bbins, int nb,
                                             int* __restrict__ boff, int* __restrict__ btot) {
    __shared__ int sb[256];
    const int t = threadIdx.x, j = blockIdx.x;
    int v = (t < nb) ? bbins[t * NBIN + j] : 0;
    sb[t] = v;
    __syncthreads();
    for (int off = 1; off < 256; off <<= 1) {
        int u = (t >= off) ? sb[t - off] : 0;
        __syncthreads();
        sb[t] += u;
        __syncthreads();
    }
    if (t < nb) boff[t * NBIN + j] = sb[t] - v;
    if (t == 255) btot[j] = sb[255];
}

__global__ __launch_bounds__(256) void k_p2b(const int* __restrict__ btot, int E,
                                             int* __restrict__ bbase, int* __restrict__ rowptr) {
    __shared__ int sb[256];
    const int t = threadIdx.x;
    int v = (t < NBIN) ? btot[t] : 0;
    sb[t] = v;
    __syncthreads();
    for (int off = 1; off < 256; off <<= 1) {
        int u = (t >= off) ? sb[t - off] : 0;
        __syncthreads();
        sb[t] += u;
        __syncthreads();
    }
    if (t < NBIN) bbase[t] = sb[t] - v;
    if (t == 0) { bbase[NBIN] = E; rowptr[N_NODES] = E; }
}

// p3: local counting sort by bucket; mine[] statically indexed (16 = BKE/256 slots)
__global__ __launch_bounds__(256) void k_p3(const int* __restrict__ src, const int* __restrict__ dst,
                                            int E, const int* __restrict__ boff,
                                            const int* __restrict__ bbase,
                                            unsigned int* __restrict__ bE) {
    __shared__ unsigned int stage[BKE];
    __shared__ int hist[256], pref[256], cur[256], sb[256], offr[NBIN];
    const int t = threadIdx.x, b = blockIdx.x;
    hist[t] = 0;
    if (t < NBIN) offr[t] = boff[b * NBIN + t] + bbase[t];
    __syncthreads();
    const int e0 = b * BKE, e1 = min(e0 + BKE, E), n = e1 - e0;
    unsigned int mine[16];
#pragma unroll
    for (int u = 0; u < 16; ++u) {
        int e = e0 + u * 256 + t;
        if (e < e1) {
            unsigned int v = ((unsigned int)src[e] << 16) | (unsigned int)dst[e];
            mine[u] = v;
            atomicAdd(&hist[(v >> 8) & 255], 1);
        }
    }
    __syncthreads();
    sb[t] = hist[t];
    __syncthreads();
    for (int off = 1; off < 256; off <<= 1) {
        int v = (t >= off) ? sb[t - off] : 0;
        __syncthreads();
        sb[t] += v;
        __syncthreads();
    }
    pref[t] = sb[t] - hist[t];
    cur[t] = pref[t];
    __syncthreads();
#pragma unroll
    for (int u = 0; u < 16; ++u) {
        int e = e0 + u * 256 + t;
        if (e < e1) {
            unsigned int v = mine[u];
            int p = atomicAdd(&cur[(v >> 8) & 255], 1);
            stage[p] = v;
        }
    }
    __syncthreads();
    for (int i = t; i < n; i += 256) {
        unsigned int v = stage[i];
        int bin = (v >> 8) & 255;
        bE[offr[bin] + (i - pref[bin])] = v;
    }
}

// p4: per-bucket sort by node -> rowptr, dinv, eidx (uint16 src ids)
__global__ __launch_bounds__(256) void k_p4(const unsigned int* __restrict__ bE,
                                            const int* __restrict__ bbase,
                                            int* __restrict__ rowptr, unsigned short* __restrict__ eidx,
                                            float* __restrict__ dinv) {
    __shared__ int hist[256], pref[256], cur[256], sb[256];
    const int t = threadIdx.x, b = blockIdx.x;
    const int eBase = bbase[b], eEnd = bbase[b + 1], n = eEnd - eBase;
    hist[t] = 0;
    __syncthreads();
    for (int i = t; i < n; i += 256) atomicAdd(&hist[bE[eBase + i] & 255], 1);
    __syncthreads();
    sb[t] = hist[t];
    __syncthreads();
    for (int off = 1; off < 256; off <<= 1) {
        int v = (t >= off) ? sb[t - off] : 0;
        __syncthreads();
        sb[t] += v;
        __syncthreads();
    }
    pref[t] = sb[t] - hist[t];
    cur[t] = pref[t];
    int node = (b << 8) + t;
    if (node < N_NODES) {
        rowptr[node] = eBase + pref[t];
        dinv[node] = rsqrtf((float)(hist[t] + 1));   // +1 self loop
    }
    __syncthreads();
    for (int i = t; i < n; i += 256) {
        unsigned int v = bE[eBase + i];
        int p = atomicAdd(&cur[v & 255], 1);
        eidx[eBase + p] = (unsigned short)(v >> 16);
    }
}

// MFMA bf16 GEMM (layer 1): hs[i][c] = f2b(dinv[i]*sum_k X[i][k]*W1[k][c]), [N][HP] bf16
__global__ __launch_bounds__(256) void k_gemm(const float* __restrict__ A,   // [N][128] f32
                                              const unsigned short* __restrict__ Wt, // [112][128]
                                              const float* __restrict__ dinv,
                                              unsigned short* __restrict__ out) {
    __shared__ __align__(16) unsigned short xs[64][136];
    __shared__ __align__(16) unsigned short ws[112][136];
    const int t = threadIdx.x;
    const int base = blockIdx.x * 64;

    for (int idx = t; idx < 112 * 64; idx += 256) {
        int c = idx >> 6, u = idx & 63;
        *(unsigned int*)&ws[c][2 * u] = ((const unsigned int*)Wt)[idx];
    }
    for (int idx = t; idx < 64 * 32; idx += 256) {
        int r = idx >> 5, q = idx & 31;
        int row = base + r;
        ushort4 p;
        if (row < N_NODES) {
            float4 v = ((const float4*)(A + (size_t)row * 128))[q];
            p.x = f2b(v.x); p.y = f2b(v.y); p.z = f2b(v.z); p.w = f2b(v.w);
        } else p = make_ushort4(0, 0, 0, 0);
        *(ushort4*)&xs[r][4 * q] = p;
    }
    __syncthreads();

    const int lane = t & 63, w = t >> 6;
    const int g = lane >> 4, cl = lane & 15;

    floatx4 acc[7];
#pragma unroll
    for (int n = 0; n < 7; ++n) acc[n] = (floatx4){0.f, 0.f, 0.f, 0.f};

#pragma unroll
    for (int kc = 0; kc < 4; ++kc) {
        short8 a = *(const short8*)&xs[w * 16 + cl][kc * 32 + 8 * g];
#pragma unroll
        for (int n = 0; n < 7; ++n) {
            short8 b = *(const short8*)&ws[n * 16 + cl][kc * 32 + 8 * g];
            acc[n] = __builtin_amdgcn_mfma_f32_16x16x32_bf16(a, b, acc[n], 0, 0, 0);
        }
    }

    float di[4]; int grows[4];
#pragma unroll
    for (int r = 0; r < 4; ++r) {
        grows[r] = base + w * 16 + 4 * g + r;
        di[r] = (grows[r] < N_NODES) ? dinv[grows[r]] : 0.0f;
    }
#pragma unroll
    for (int n = 0; n < 7; ++n) {
        int gcol = n * 16 + cl;
        if (gcol >= HP) continue;
#pragma unroll
        for (int r = 0; r < 4; ++r) {
            if (grows[r] < N_NODES)
                out[(size_t)grows[r] * HP + gcol] = f2b(acc[n][r] * di[r]);
        }
    }
}

#define ACC8(v) do { \
    s[0] += b2f((v).x & 0xffff); s[1] += b2f((v).x >> 16); \
    s[2] += b2f((v).y & 0xffff); s[3] += b2f((v).y >> 16); \
    s[4] += b2f((v).z & 0xffff); s[5] += b2f((v).z >> 16); \
    s[6] += b2f((v).w & 0xffff); s[7] += b2f((v).w >> 16); } while (0)

// Fused layer-1 gather + tanh + layer-2 matvec (H1 never materialized; round-11's
// k_q and the 10.4MB H1 write/read are gone). Block = 512 thr = 39 nodes x 13 chunks.
// q[i] = dinv[i] * sum_j tanh(dinv[i]*(self+sum_src)[j] + b1[j]) * w2l[j]
// 16-deep edge unroll (mean deg 16) -> 16 independent loads in flight.
__global__ __launch_bounds__(512) void k_gather_q(const int* __restrict__ rowptr,
                                                  const unsigned short* __restrict__ eidx,
                                                  const unsigned short* __restrict__ hs,
                                                  const float* __restrict__ dinv,
                                                  const float* __restrict__ b1,
                                                  const float* __restrict__ w2l,
                                                  float* __restrict__ q) {
    __shared__ float wl[104];
    __shared__ float bsh[104];
    __shared__ float part[512];
    const int t = threadIdx.x;
    if (t < 104) { wl[t] = w2l[t]; bsh[t] = (t < 100) ? b1[t] : 0.0f; }
    const int nid = t / 13, c = t - nid * 13;
    const int i = blockIdx.x * NPB + nid;
    const bool active = (t < NPB * 13) && (i < N_NODES);
    __syncthreads();

    float partial = 0.0f;
    float di = 0.0f;
    if (active) {
        const int c0 = 8 * c;
        float s[8] = {0.f, 0.f, 0.f, 0.f, 0.f, 0.f, 0.f, 0.f};
        uint4 sv = *(const uint4*)(hs + (size_t)i * HP + c0);   // self loop
        ACC8(sv);
        int e = rowptr[i];
        const int end = rowptr[i + 1];
        for (; e + 16 <= end; e += 16) {
            int n[16];
#pragma unroll
            for (int u = 0; u < 16; ++u) n[u] = eidx[e + u];
            uint4 v[16];
#pragma unroll
            for (int u = 0; u < 16; ++u) v[u] = *(const uint4*)(hs + (size_t)n[u] * HP + c0);
#pragma unroll
            for (int u = 0; u < 16; ++u) ACC8(v[u]);
        }
        for (; e + 8 <= end; e += 8) {
            int n[8];
#pragma unroll
            for (int u = 0; u < 8; ++u) n[u] = eidx[e + u];
            uint4 v[8];
#pragma unroll
            for (int u = 0; u < 8; ++u) v[u] = *(const uint4*)(hs + (size_t)n[u] * HP + c0);
#pragma unroll
            for (int u = 0; u < 8; ++u) ACC8(v[u]);
        }
        for (; e + 4 <= end; e += 4) {
            int n[4];
#pragma unroll
            for (int u = 0; u < 4; ++u) n[u] = eidx[e + u];
            uint4 v[4];
#pragma unroll
            for (int u = 0; u < 4; ++u) v[u] = *(const uint4*)(hs + (size_t)n[u] * HP + c0);
#pragma unroll
            for (int u = 0; u < 4; ++u) ACC8(v[u]);
        }
        for (; e < end; ++e) {
            uint4 v = *(const uint4*)(hs + (size_t)eidx[e] * HP + c0);
            ACC8(v);
        }
        di = dinv[i];
#pragma unroll
        for (int j = 0; j < 8; ++j) {
            float h = tanhf(di * s[j] + bsh[c0 + j]);   // pad cols: s=0,b=0 -> h=0, wl=0
            partial += h * wl[c0 + j];
        }
    }
    part[t] = partial;
    __syncthreads();
    if (active && c == 0) {
        float sum = 0.0f;
#pragma unroll
        for (int j = 0; j < 13; ++j) sum += part[t + j];
        q[i] = di * sum;
    }
}

// fused layer-2 aggregate + mean-pool: scalar gather from 200KB q table, 8-deep MLP
__global__ __launch_bounds__(256) void k_gpool(const int* __restrict__ rowptr,
                                               const unsigned short* __restrict__ eidx,
                                               const float* __restrict__ q,
                                               const float* __restrict__ dinv,
                                               const int* __restrict__ batch,
                                               float* __restrict__ pool,
                                               float* __restrict__ cntf) {
    __shared__ float sp[N_GRAPHS];
    __shared__ float sc[N_GRAPHS];
    const int t = threadIdx.x;
    if (t < N_GRAPHS) { sp[t] = 0.0f; sc[t] = 0.0f; }
    __syncthreads();
    int i = blockIdx.x * 256 + t;
    if (i < N_NODES) {
        float s = q[i];
        int e = rowptr[i];
        const int end = rowptr[i + 1];
        for (; e + 8 <= end; e += 8) {
            int n0 = eidx[e],     n1 = eidx[e + 1], n2 = eidx[e + 2], n3 = eidx[e + 3];
            int n4 = eidx[e + 4], n5 = eidx[e + 5], n6 = eidx[e + 6], n7 = eidx[e + 7];
            s += q[n0] + q[n1] + q[n2] + q[n3] + q[n4] + q[n5] + q[n6] + q[n7];
        }
        for (; e + 4 <= end; e += 4) {
            int n0 = eidx[e], n1 = eidx[e + 1], n2 = eidx[e + 2], n3 = eidx[e + 3];
            s += q[n0] + q[n1] + q[n2] + q[n3];
        }
        for (; e < end; ++e) s += q[eidx[e]];
        float p = dinv[i] * s;
        int g = batch[i];
        atomicAdd(&sp[g], p);
        atomicAdd(&sc[g], 1.0f);
    }
    __syncthreads();
    if (t < N_GRAPHS && sc[t] != 0.0f) {
        atomicAdd(&pool[t], sp[t]);
        atomicAdd(&cntf[t], sc[t]);
    }
}

__global__ void k_final(const float* __restrict__ pool, const float* __restrict__ cnt,
                        const float* __restrict__ w2l, const float* __restrict__ blin,
                        float* __restrict__ out) {
    int g = threadIdx.x;
    if (g >= N_GRAPHS) return;
    out[g] = pool[g] / fmaxf(cnt[g], 1.0f) + w2l[104] + blin[0];
}

extern "C" void kernel_launch(void* const* d_in, const int* in_sizes, int n_in,
                              void* d_out, int out_size, void* d_ws, size_t ws_size,
                              hipStream_t stream) {
    const float* x    = (const float*)d_in[0];
    const int*   ei   = (const int*)d_in[1];
    const int*   batch= (const int*)d_in[2];
    const float* W1   = (const float*)d_in[3];
    const float* b1   = (const float*)d_in[4];
    const float* W2   = (const float*)d_in[5];
    const float* b2   = (const float*)d_in[6];
    const float* Wlin = (const float*)d_in[7];
    const float* blin = (const float*)d_in[8];
    float* out = (float*)d_out;

    const int E = in_sizes[1] / 2;
    const int* src = ei;
    const int* dst = ei + E;

    float* wsf  = (float*)d_ws;
    int*   wsi  = (int*)d_ws;
    float* dinv = wsf + OFF_DINV;
    float* cntf = wsf + OFF_CNTF;
    float* pool = wsf + OFF_POOL;
    unsigned short* Wt1 = (unsigned short*)(wsf + OFF_WT1);
    unsigned short* HS  = (unsigned short*)(wsf + OFF_HS);
    int* rowptr = wsi + OFF_ROWPTR;
    unsigned short* eidx = (unsigned short*)(wsi + OFF_EIDX);
    unsigned int* bE = (unsigned int*)(wsi + OFF_BE);
    int* bbins  = wsi + OFF_BBINS;
    int* boff   = wsi + OFF_BOFF;
    int* btot   = wsi + OFF_BTOT;
    int* bbase  = wsi + OFF_BBASE;
    float* w2l  = wsf + OFF_W2L;
    float* q    = wsf + OFF_Q;

    const int nbE = (E + BKE - 1) / BKE;   // 196 for E=800k (<= MAXBLK)
    const int nGrid = (N_NODES + 255) / 256;
    const int gqGrid = (N_NODES + NPB - 1) / NPB;   // 1283

    // prep (Wt1 + w2l + pool/cnt zero) and CSR build
    k_prep<<<57, 256, 0, stream>>>(W1, W2, Wlin, b2, Wt1, w2l, pool, cntf);
    k_p1<<<nbE, 256, 0, stream>>>(dst, E, bbins);
    k_p2a<<<NBIN, 256, 0, stream>>>(bbins, nbE, boff, btot);
    k_p2b<<<1, 256, 0, stream>>>(btot, E, bbase, rowptr);
    k_p3<<<nbE, 256, 0, stream>>>(src, dst, E, boff, bbase, bE);
    k_p4<<<NBIN, 256, 0, stream>>>(bE, bbase, rowptr, eidx, dinv);

    // layer 1 GEMM
    k_gemm<<<(N_NODES + 63) / 64, 256, 0, stream>>>(x, Wt1, dinv, HS);

    // fused gather + tanh + layer-2 matvec -> q
    k_gather_q<<<gqGrid, 512, 0, stream>>>(rowptr, eidx, HS, dinv, b1, w2l, q);

    // fused layer-2 aggregate + mean-pool
    k_gpool<<<nGrid, 256, 0, stream>>>(rowptr, eidx, q, dinv, batch, pool, cntf);

    // readout
    k_final<<<1, 64, 0, stream>>>(pool, cntf, w2l, blin, out);
}